// Round 1
// baseline (1656.492 us; speedup 1.0000x reference)
//
#include <hip/hip_runtime.h>

#define T_DIM 256
#define B_DIM 32
#define D_DIM 512
#define K_DIM 512
#define M_DIM 8192      // T*B
#define N_DIM 32000     // vocab
#define SOS_TOK 32000
#define GAMMA 0.4f

#define BM 128
#define BN 128
#define BK 64

typedef __attribute__((ext_vector_type(8))) short short8;
typedef __attribute__((ext_vector_type(4))) float floatx4;
typedef __attribute__((ext_vector_type(8))) unsigned short ushortx8;

__device__ __forceinline__ unsigned short f32_to_bf16(float f) {
    unsigned int u = __float_as_uint(f);
    u += 0x7FFFu + ((u >> 16) & 1u);   // round-to-nearest-even
    return (unsigned short)(u >> 16);
}

__device__ __forceinline__ void async_copy16(const void* g, void* l) {
    __builtin_amdgcn_global_load_lds(
        (const __attribute__((address_space(1))) void*)g,
        (__attribute__((address_space(3))) void*)l,
        16, 0, 0);
}

// ---------------------------------------------------------------------------
// Kernel 1: states[t*B+b, d] in bf16.
//   enc[b,d]   = sum_{t<in_len} gamma^t * E[inp[t,b], d]
//   states[t]  = enc + cumsum_t( -(gamma^(t-1)) * E[x[t],d] * (t < out_len) )
//   x[0]=SOS, x[t]=outp[t-1]
// grid (B, D/128), block 128 — per-block b is uniform (no divergence).
// ---------------------------------------------------------------------------
__global__ void states_kernel(const int* __restrict__ inp,
                              const int* __restrict__ in_len,
                              const int* __restrict__ outp,
                              const int* __restrict__ out_len,
                              const float* __restrict__ E,
                              unsigned short* __restrict__ Abf) {
    const int b = blockIdx.x;
    const int d = blockIdx.y * blockDim.x + threadIdx.x;
    const int Lin = in_len[b];
    const int Lout = out_len[b];

    float enc = 0.f;
    float c = 1.f;
    for (int t = 0; t < Lin; ++t) {
        int tok = inp[t * B_DIM + b];
        enc = fmaf(c, E[(size_t)tok * D_DIM + d], enc);
        c *= GAMMA;
    }

    float s = enc;
    float coef = -2.5f;  // -(gamma^-1)
    int t = 0;
    for (; t < Lout; ++t) {
        int tok = (t == 0) ? SOS_TOK : outp[(t - 1) * B_DIM + b];
        s = fmaf(coef, E[(size_t)tok * D_DIM + d], s);
        coef *= GAMMA;
        Abf[((size_t)t * B_DIM + b) * D_DIM + d] = f32_to_bf16(s);
    }
    // states frozen past out_len
    const unsigned short sb = f32_to_bf16(s);
    for (; t < T_DIM; ++t) {
        Abf[((size_t)t * B_DIM + b) * D_DIM + d] = sb;
    }
}

// ---------------------------------------------------------------------------
// Kernel 2: W fp32 -> bf16 (16,384,000 elems, 8/thread)
// ---------------------------------------------------------------------------
__global__ void convert_w(const float* __restrict__ W,
                          unsigned short* __restrict__ Wbf) {
    size_t i = ((size_t)blockIdx.x * blockDim.x + threadIdx.x) * 8;
    float4 v0 = *(const float4*)(W + i);
    float4 v1 = *(const float4*)(W + i + 4);
    ushortx8 o;
    o[0] = f32_to_bf16(v0.x); o[1] = f32_to_bf16(v0.y);
    o[2] = f32_to_bf16(v0.z); o[3] = f32_to_bf16(v0.w);
    o[4] = f32_to_bf16(v1.x); o[5] = f32_to_bf16(v1.y);
    o[6] = f32_to_bf16(v1.z); o[7] = f32_to_bf16(v1.w);
    *(ushortx8*)(Wbf + i) = o;
}

// ---------------------------------------------------------------------------
// Kernel 3: C[m,n] = sum_k A[m,k]*Wb[n,k] + bias[n]   (m97-style bf16 MFMA)
// 128x128 block tile, 4 waves in 2x2, each wave 4x4 of 16x16x32 MFMA, BK=64.
// ---------------------------------------------------------------------------
__global__ __launch_bounds__(256) void gemm_kernel(
        const unsigned short* __restrict__ A,    // [M_DIM, K_DIM] bf16
        const unsigned short* __restrict__ Wb,   // [N_DIM, K_DIM] bf16
        const float* __restrict__ bias,          // [N_DIM]
        float* __restrict__ out) {               // [M_DIM, N_DIM]
    __shared__ unsigned short As[BM * BK];
    __shared__ unsigned short Ws[BN * BK];

    const int tid  = threadIdx.x;
    const int lane = tid & 63;
    const int wave = tid >> 6;
    const int wm   = wave & 1;
    const int wn   = wave >> 1;
    const int row16 = lane & 15;
    const int quad  = lane >> 4;

    const int m0 = blockIdx.y * BM;
    const int n0 = blockIdx.x * BN;

    floatx4 acc[4][4];
#pragma unroll
    for (int i = 0; i < 4; ++i)
#pragma unroll
        for (int j = 0; j < 4; ++j)
            acc[i][j] = (floatx4){0.f, 0.f, 0.f, 0.f};

    for (int kb = 0; kb < K_DIM / BK; ++kb) {
        const int k0 = kb * BK;
        __syncthreads();   // prior compute done before overwriting LDS
#pragma unroll
        for (int it = 0; it < 4; ++it) {
            int slot = tid + it * 256;     // 0..1023, 16B each
            int row  = slot >> 3;          // 0..127
            int c8   = slot & 7;           // col8 group
            async_copy16(A  + (size_t)(m0 + row) * K_DIM + k0 + c8 * 8,
                         As + slot * 8);
            async_copy16(Wb + (size_t)(n0 + row) * K_DIM + k0 + c8 * 8,
                         Ws + slot * 8);
        }
        __syncthreads();   // vmcnt(0) drain + barrier

#pragma unroll
        for (int kk = 0; kk < BK; kk += 32) {
            short8 af[4], wf[4];
#pragma unroll
            for (int i = 0; i < 4; ++i)
                af[i] = *(const short8*)(As + (wm * 64 + i * 16 + row16) * BK + kk + quad * 8);
#pragma unroll
            for (int j = 0; j < 4; ++j)
                wf[j] = *(const short8*)(Ws + (wn * 64 + j * 16 + row16) * BK + kk + quad * 8);
#pragma unroll
            for (int i = 0; i < 4; ++i)
#pragma unroll
                for (int j = 0; j < 4; ++j)
                    acc[i][j] = __builtin_amdgcn_mfma_f32_16x16x32_bf16(
                        af[i], wf[j], acc[i][j], 0, 0, 0);
        }
    }

    // Epilogue: C/D layout col=lane&15, row=quad*4+reg
#pragma unroll
    for (int j = 0; j < 4; ++j) {
        const int col = n0 + wn * 64 + j * 16 + row16;
        const float bv = bias[col];
#pragma unroll
        for (int i = 0; i < 4; ++i) {
            const int mrow = m0 + wm * 64 + i * 16 + quad * 4;
#pragma unroll
            for (int r = 0; r < 4; ++r) {
                out[(size_t)(mrow + r) * N_DIM + col] = acc[i][j][r] + bv;
            }
        }
    }
}

// ---------------------------------------------------------------------------
extern "C" void kernel_launch(void* const* d_in, const int* in_sizes, int n_in,
                              void* d_out, int out_size, void* d_ws, size_t ws_size,
                              hipStream_t stream) {
    const int*   inp     = (const int*)d_in[0];
    const int*   in_len  = (const int*)d_in[1];
    const int*   outp    = (const int*)d_in[2];
    const int*   out_len = (const int*)d_in[3];
    const float* E       = (const float*)d_in[4];
    const float* W       = (const float*)d_in[5];
    const float* bias    = (const float*)d_in[6];
    float*       out     = (float*)d_out;

    unsigned short* Abf = (unsigned short*)d_ws;                       // 8,388,608 B
    unsigned short* Wbf = (unsigned short*)((char*)d_ws + (size_t)M_DIM * K_DIM * 2);

    hipLaunchKernelGGL(states_kernel, dim3(B_DIM, D_DIM / 128), dim3(128), 0, stream,
                       inp, in_len, outp, out_len, E, Abf);
    hipLaunchKernelGGL(convert_w, dim3((N_DIM * K_DIM / 8) / 256), dim3(256), 0, stream,
                       W, Wbf);
    hipLaunchKernelGGL(gemm_kernel, dim3(N_DIM / BN, M_DIM / BM), dim3(256), 0, stream,
                       Abf, Wbf, bias, out);
}